// Round 7
// baseline (222.935 us; speedup 1.0000x reference)
//
#include <hip/hip_runtime.h>
#include <cstdint>
#include <cstddef>

#define HID 1024
#define SEQ 4096
#define NB  2
#define NH  16
#define HD  64
#define WIN 512
#define TOK (NB*SEQ)   // 8192 tokens

typedef _Float16 f16x8 __attribute__((ext_vector_type(8)));
typedef _Float16 f16x4 __attribute__((ext_vector_type(4)));
typedef float    f32x4 __attribute__((ext_vector_type(4)));

// ---------- fp32 -> fp16 conversion (single launch: X + 4 weights) ----------
__global__ __launch_bounds__(256)
void convert_kernel(const float* __restrict__ X, const float* __restrict__ w0,
                    const float* __restrict__ w1, const float* __restrict__ w2,
                    const float* __restrict__ w3,
                    _Float16* __restrict__ Xh, _Float16* __restrict__ Wh) {
  const int bi = blockIdx.x;
  const float* src; _Float16* dst; size_t off;
  if (bi < 4096) {                     // X: 8M f32
    src = X; dst = Xh; off = (size_t)bi * 2048;
  } else {                             // W0..W3: 1M f32 each
    const int wi = bi - 4096, z = wi >> 9;
    src = (z == 0) ? w0 : (z == 1) ? w1 : (z == 2) ? w2 : w3;
    dst = Wh + (size_t)z * HID * HID;
    off = (size_t)(wi & 511) * 2048;
  }
  const size_t i = off + (size_t)threadIdx.x * 8;
  f32x4 a = *(const f32x4*)(src + i);
  f32x4 b = *(const f32x4*)(src + i + 4);
  f16x8 o;
#pragma unroll
  for (int r = 0; r < 4; ++r) { o[r] = (_Float16)a[r]; o[r+4] = (_Float16)b[r]; }
  *(f16x8*)(dst + i) = o;
}

// async global->LDS, 16B per lane (m97-verified; LDS dest = uniform base + lane*16)
__device__ __forceinline__ void gload16(const void* g, void* lds) {
  __builtin_amdgcn_global_load_lds(
      (__attribute__((address_space(1))) void*)(void*)g,
      (__attribute__((address_space(3))) void*)lds, 16, 0, 0);
}

// ---------- C = A @ W^T main loop, BK=64 as two m97-pattern 8KB sub-tiles ----
// ROUND-7: occupancy fix. R6 counters: qkv OccupancyPercent 24.6% = 8
// waves/CU = 2 blocks resident. Cause: unified VGPR/AGPR file -- combined
// footprint = 72 VGPR + 64 AGPR(acc) = 136 > 128 -> 2 waves/SIMD (m69
// steps: <=64:8, <=128:4, <=256:2). LDS (32KB -> 5 blocks) was never the
// limiter. __launch_bounds__(256,4) forces combined <=128 (64+64): the
// non-acc live set (~50: 4 gptrs, 4 LDS addrs, 16 frag regs, misc) has
// room. 4 blocks/CU doubles cross-block hiding of the per-K-step
// vmcnt(0)+barrier drain (this structure's known ~20% stall).
// Spill tripwire: WRITE_SIZE inflation (R3 signature) -> revert.
__device__ __forceinline__ void gemm_mainloop(
    const _Float16* __restrict__ A, const _Float16* __restrict__ W,
    _Float16* sA, _Float16* sB, f32x4 (&acc)[4][4], int m0, int n0) {
  const int tid  = threadIdx.x;
  const int lane = tid & 63;
  const int wave = tid >> 6;
  const int wm = wave >> 1, wn = wave & 1;
  const int l15 = lane & 15, quad = lane >> 4;

  const int o0 = tid * 16;
  const int o1 = o0 + 4096;
  const _Float16* a0 = A + (size_t)(m0 + (o0 >> 6)) * HID + ((o0 & 63) >> 1);
  const _Float16* a1 = A + (size_t)(m0 + (o1 >> 6)) * HID + ((o1 & 63) >> 1);
  const _Float16* w0 = W + (size_t)(n0 + (o0 >> 6)) * HID + ((o0 & 63) >> 1);
  const _Float16* w1 = W + (size_t)(n0 + (o1 >> 6)) * HID + ((o1 & 63) >> 1);
  _Float16* la0 = sA + (o0 >> 1);
  _Float16* la1 = sA + (o1 >> 1);
  _Float16* lb0 = sB + (o0 >> 1);
  _Float16* lb1 = sB + (o1 >> 1);

  const int aoff = (wm*64 + l15)*32 + quad*8;
  const int boff = (wn*64 + l15)*32 + quad*8;

  for (int k0 = 0; k0 < HID; k0 += 64) {
    __syncthreads();                 // WAR: prior iter's LDS reads done
    gload16(a0 + k0,      la0);
    gload16(a1 + k0,      la1);
    gload16(a0 + k0 + 32, la0 + 4096);
    gload16(a1 + k0 + 32, la1 + 4096);
    gload16(w0 + k0,      lb0);
    gload16(w1 + k0,      lb1);
    gload16(w0 + k0 + 32, lb0 + 4096);
    gload16(w1 + k0 + 32, lb1 + 4096);
    __syncthreads();                 // staging complete
#pragma unroll
    for (int s = 0; s < 2; ++s) {
      const int sb = s * 4096;
      f16x8 af[4], wf[4];
#pragma unroll
      for (int t = 0; t < 4; ++t) {
        af[t] = *(const f16x8*)(sA + sb + aoff + t*512);
        wf[t] = *(const f16x8*)(sB + sb + boff + t*512);
      }
#pragma unroll
      for (int i = 0; i < 4; ++i)
#pragma unroll
        for (int j = 0; j < 4; ++j)
          acc[i][j] = __builtin_amdgcn_mfma_f32_16x16x32_f16(af[i], wf[j], acc[i][j], 0, 0, 0);
    }
  }
}

// QKV, 1536 blocks. XCD g owns X m-slab g (2MB L2-resident); W streams.
__global__ __launch_bounds__(256, 4)
void gemm_qkv_kernel(const _Float16* __restrict__ X,
                     const _Float16* __restrict__ Wh,
                     _Float16* __restrict__ Q,
                     _Float16* __restrict__ Kb,
                     _Float16* __restrict__ Vt) {
  __shared__ __align__(16) _Float16 sA[128*64];
  __shared__ __align__(16) _Float16 sB[128*64];
  const int i  = blockIdx.x;
  const int g  = i & 7;
  const int j  = i >> 3;
  const int mi = j & 7;
  const int c  = j >> 3;
  const int z  = c >> 3;
  const int n0 = (c & 7) * 128;
  const int m0 = (g*8 + mi) * 128;
  const _Float16* W = Wh + (size_t)z * HID * HID;
  f32x4 acc[4][4] = {};
  gemm_mainloop(X, W, sA, sB, acc, m0, n0);

  const int tid  = threadIdx.x;
  const int lane = tid & 63;
  const int wave = tid >> 6;
  const int wm = wave >> 1, wn = wave & 1;
  const int l15 = lane & 15, quad = lane >> 4;

  if (z < 2) {
    _Float16* C = (z == 0) ? Q : Kb;
    // z==0: fold softmax scale AND log2(e) into Q (exp2-domain softmax)
    const float scl = (z == 0) ? 0.18033688011f : 1.0f;
#pragma unroll
    for (int tm = 0; tm < 4; ++tm)
#pragma unroll
      for (int tn = 0; tn < 4; ++tn) {
        const int row = m0 + wm*64 + tm*16 + quad*4;
        const int col = n0 + wn*64 + tn*16 + l15;
#pragma unroll
        for (int r = 0; r < 4; ++r)
          C[(size_t)(row + r)*HID + col] = (_Float16)(acc[tm][tn][r] * scl);
      }
  } else {
#pragma unroll
    for (int tm = 0; tm < 4; ++tm)
#pragma unroll
      for (int tn = 0; tn < 4; ++tn) {
        const int row = m0 + wm*64 + tm*16 + quad*4;   // token
        const int col = n0 + wn*64 + tn*16 + l15;      // feature
        f16x4 v;
#pragma unroll
        for (int r = 0; r < 4; ++r) v[r] = (_Float16)acc[tm][tn][r];
        *(f16x4*)(Vt + (size_t)col*TOK + row) = v;
      }
  }
}

// O-proj, 512 blocks: XCD g owns A m-slab g; Wo streams.
__global__ __launch_bounds__(256, 4)
void gemm_o_kernel(const _Float16* __restrict__ A,
                   const _Float16* __restrict__ Wo,
                   float* __restrict__ C) {
  __shared__ __align__(16) _Float16 sA[128*64];
  __shared__ __align__(16) _Float16 sB[128*64];
  const int i  = blockIdx.x;
  const int g  = i & 7;
  const int j  = i >> 3;
  const int mi = j & 7;
  const int n0 = (j >> 3) * 128;
  const int m0 = (g*8 + mi) * 128;
  f32x4 acc[4][4] = {};
  gemm_mainloop(A, Wo, sA, sB, acc, m0, n0);

  const int tid  = threadIdx.x;
  const int lane = tid & 63;
  const int wave = tid >> 6;
  const int wm = wave >> 1, wn = wave & 1;
  const int l15 = lane & 15, quad = lane >> 4;
#pragma unroll
  for (int tm = 0; tm < 4; ++tm)
#pragma unroll
    for (int tn = 0; tn < 4; ++tn) {
      const int row = m0 + wm*64 + tm*16 + quad*4;
      const int col = n0 + wn*64 + tn*16 + l15;
#pragma unroll
      for (int r = 0; r < 4; ++r)
        C[(size_t)(row + r)*HID + col] = acc[tm][tn][r];
    }
}

// ---------- Flash sliding-window attention, S^T orientation ----------
// (R6 structure kept verbatim: wave=16 queries, 128 q/block, grid 1024,
//  P buffer 8KB with chunk^(l15&3) swizzle, per-wave __all AM precheck,
//  LDS 40960B. R6 result: attn dropped out of top-5, ~50us est.)
__global__ __launch_bounds__(512, 4)
void attn_kernel(const _Float16* __restrict__ Q, const _Float16* __restrict__ Kb,
                 const _Float16* __restrict__ Vt, const int* __restrict__ AM,
                 _Float16* __restrict__ O) {
  __shared__ __align__(16) _Float16 sK[128*64];    // 16KB [key 0..127][d]
  __shared__ __align__(16) _Float16 sV[64*128];    // 16KB [dfeat][key 0..127]
  __shared__ __align__(16) _Float16 sP[8*16*32];   // 8KB  per-wave 16q x 32k

  const int bi = blockIdx.x;
  const int g  = bi & 7;                // XCD
  const int jj = bi >> 3;               // 0..127
  const int combo = g*4 + (jj >> 5);    // 0..31 -> (b,h), XCD-affine
  const int h = combo & 15, b = combo >> 4;
  const int qb = jj & 31;               // q-block (128 queries)

  const int tid  = threadIdx.x;
  const int lane = tid & 63, wave = tid >> 6;
  const int l15 = lane & 15, quad = lane >> 4;

  const int q0 = qb * 128;
  const int qw = q0 + wave * 16;        // wave's first (and only) q-tile

  const int swz = l15 & 7;
  const int cA8 = ((quad ^ swz) << 3);
  const int cB8 = (((quad + 4) ^ swz) << 3);

  // Q fragments: B[n=query=l15][k=d=quad*8+j]; Q pre-scaled by 0.125*log2(e).
  f16x8 qf0, qf1;
  {
    const size_t qbse = (size_t)(b*SEQ + qw + l15)*HID + h*HD + quad*8;
    qf0 = *(const f16x8*)(Q + qbse);
    qf1 = *(const f16x8*)(Q + qbse + 32);
  }

  // 128-key stages covering [stage_lo, q0+128)
  int stage_lo = (q0 - (WIN - 1));
  stage_lo = (stage_lo < 0) ? 0 : (stage_lo & ~127);
  const int nst = (q0 + 128 - stage_lo) >> 7;   // <= 5

  // per-wave attention_mask all-ones precheck (<=10 iters, no barriers)
  int okv = 1;
  for (int j = stage_lo + lane; j < q0 + 128; j += 64) okv &= (AM[b*SEQ + j] != 0);
  const bool allok = (__all(okv) != 0);

  // staging: thread stages 2x16B of K (rows prow, prow+64) and 2x16B of V.
  const int prow = tid >> 3;            // 0..63
  const int pc   = tid & 7;
  const int pco  = ((pc ^ (prow & 7)) << 3);   // swizzled GLOBAL chunk offset
  f16x8 pk0, pk1, pv0, pv1;
  {
    const _Float16* kp = Kb + (size_t)(b*SEQ + stage_lo + prow)*HID + h*HD + pco;
    pk0 = *(const f16x8*)kp;
    pk1 = *(const f16x8*)(kp + (size_t)64*HID);
    const _Float16* vp = Vt + (size_t)(h*HD + prow)*TOK + b*SEQ + stage_lo + pco;
    pv0 = *(const f16x8*)vp;
    pv1 = *(const f16x8*)(vp + 64);
  }

  float l_run = 0.0f;
  f32x4 o[4] = {};
  _Float16* myP = sP + wave * (16*32);

  for (int st = 0; st < nst; ++st) {
    const int j0st = stage_lo + st*128;
    __syncthreads();                  // WAR: prior iter's sK/sV reads done
    *(f16x8*)(sK + prow*64 + pc*8)        = pk0;   // UNSWIZZLED store position
    *(f16x8*)(sK + (64 + prow)*64 + pc*8) = pk1;
    *(f16x8*)(sV + prow*128 + pc*8)       = pv0;
    *(f16x8*)(sV + prow*128 + 64 + pc*8)  = pv1;
    __syncthreads();                  // staging visible
    if (st + 1 < nst) {
      const int jn = j0st + 128;
      const _Float16* kp = Kb + (size_t)(b*SEQ + jn + prow)*HID + h*HD + pco;
      pk0 = *(const f16x8*)kp;
      pk1 = *(const f16x8*)(kp + (size_t)64*HID);
      const _Float16* vp = Vt + (size_t)(h*HD + prow)*TOK + b*SEQ + jn + pco;
      pv0 = *(const f16x8*)vp;
      pv1 = *(const f16x8*)(vp + 64);
    }

#pragma unroll
    for (int s = 0; s < 2; ++s) {
      const int j0 = j0st + s*64;
      // wave-uniform: skip sub-tiles fully outside this wave's window
      if (j0 > qw + 15 || j0 + 63 < qw - (WIN - 1)) continue;
      // interior sub-tile: every (query,key) pair valid -> no mask needed
      const bool interior = (j0 + 63 <= qw) && (j0 >= qw - (WIN - 16));

      // S^T = K Q^T: sc[t] D[m=key=t*16+quad*4+r][n=query=l15]
      f32x4 sc[4];
#pragma unroll
      for (int t = 0; t < 4; ++t) {
        const f16x8 kf0 = *(const f16x8*)(sK + (s*64 + t*16 + l15)*64 + cA8);
        const f16x8 kf1 = *(const f16x8*)(sK + (s*64 + t*16 + l15)*64 + cB8);
        f32x4 a = {};
        a = __builtin_amdgcn_mfma_f32_16x16x32_f16(kf0, qf0, a, 0, 0, 0);
        a = __builtin_amdgcn_mfma_f32_16x16x32_f16(kf1, qf1, a, 0, 0, 0);
        sc[t] = a;
      }

      if (!allok) {
#pragma unroll
        for (int t = 0; t < 4; ++t)
#pragma unroll
          for (int r = 0; r < 4; ++r) {
            const float ad = (AM[b*SEQ + j0 + t*16 + quad*4 + r] == 0) ? -2e30f : 0.0f;
            sc[t][r] += ad;
          }
      }
      // window mask (boundary only) + static-bound softmax: p = exp2(s')
      if (!interior) {
        const int i = qw + l15;
#pragma unroll
        for (int t = 0; t < 4; ++t)
#pragma unroll
          for (int r = 0; r < 4; ++r) {
            const int j = j0 + t*16 + quad*4 + r;
            const bool valid = (unsigned)(i - j) < WIN;
            sc[t][r] = valid ? sc[t][r] : -1e30f;
          }
      }

      // per-32-key-half: exp2 -> P (1KB wave-private, chunk^(l15&3) swizzle)
      // -> PV MFMA. o accumulation order kh0,kh1 == old vf0,vf1 (bit-same).
      float sum = 0.0f;
#pragma unroll
      for (int kh = 0; kh < 2; ++kh) {
#pragma unroll
        for (int u = 0; u < 2; ++u) {
          const int t = 2*kh + u;
          f16x4 pvv;
#pragma unroll
          for (int r = 0; r < 4; ++r) {
            const float p = __builtin_amdgcn_exp2f(sc[t][r]);
            sum += p;
            pvv[r] = (_Float16)p;
          }
          // logical col (in 32-key half) = 16u + 4*quad + r; chunk-of-8 c =
          // 2u + (quad>>1), phys = c ^ (l15&3), in-chunk off = (quad&1)*4
          const int pch = (2*u + (quad >> 1)) ^ (l15 & 3);
          *(f16x4*)(myP + l15*32 + pch*8 + (quad & 1)*4) = pvv;
        }
        // B-frag: keys quad*8..+7 of this half -> phys chunk quad^(l15&3)
        const f16x8 pf = *(const f16x8*)(myP + l15*32 + ((quad ^ (l15 & 3)) << 3));
#pragma unroll
        for (int dt = 0; dt < 4; ++dt) {
          const f16x8 vf = *(const f16x8*)(sV + (dt*16 + l15)*128 + s*64 +
                                           (((kh*4 + quad) ^ swz) << 3));
          o[dt] = __builtin_amdgcn_mfma_f32_16x16x32_f16(vf, pf, o[dt], 0, 0, 0);
        }
      }
      sum += __shfl_xor(sum, 16, 64);
      sum += __shfl_xor(sum, 32, 64);
      l_run += sum;
    }
  }

  // epilogue: O^T[m=dfeat][n=query] -> O[query][feat]
  const float inv = 1.0f / fmaxf(l_run, 1e-30f);
  const size_t ob = (size_t)(b*SEQ + qw + l15)*HID + h*HD + quad*4;
#pragma unroll
  for (int dt = 0; dt < 4; ++dt) {
    f16x4 v;
#pragma unroll
    for (int r = 0; r < 4; ++r) v[r] = (_Float16)(o[dt][r] * inv);
    *(f16x4*)(O + ob + dt*16) = v;
  }
}

extern "C" void kernel_launch(void* const* d_in, const int* in_sizes, int n_in,
                              void* d_out, int out_size, void* d_ws, size_t ws_size,
                              hipStream_t stream) {
  const float* X  = (const float*)d_in[0];
  const int*   AM = (const int*)d_in[1];
  const float* Wq = (const float*)d_in[2];
  const float* Wk = (const float*)d_in[3];
  const float* Wv = (const float*)d_in[4];
  const float* Wo = (const float*)d_in[5];
  float* out = (float*)d_out;

  _Float16* Xh = (_Float16*)d_ws;
  _Float16* Wh = Xh + (size_t)TOK*HID;
  _Float16* Qb = Wh + (size_t)4*HID*HID;
  _Float16* Kb = Qb + (size_t)TOK*HID;
  _Float16* Vt = Kb + (size_t)TOK*HID;
  _Float16* AO = Vt + (size_t)TOK*HID;

  convert_kernel<<<dim3(4096 + 4*512), dim3(256), 0, stream>>>(X, Wq, Wk, Wv, Wo, Xh, Wh);
  gemm_qkv_kernel<<<dim3(1536), dim3(256), 0, stream>>>(Xh, Wh, Qb, Kb, Vt);
  attn_kernel<<<dim3(1024), dim3(512), 0, stream>>>(Qb, Kb, Vt, AM, AO);
  gemm_o_kernel<<<dim3(512), dim3(256), 0, stream>>>(AO, Wh + (size_t)3*HID*HID, out);
}

// Round 8
// 215.174 us; speedup vs baseline: 1.0361x; 1.0361x over previous
//
#include <hip/hip_runtime.h>
#include <cstdint>
#include <cstddef>

#define HID 1024
#define SEQ 4096
#define NB  2
#define NH  16
#define HD  64
#define WIN 512
#define TOK (NB*SEQ)   // 8192 tokens

typedef _Float16 f16x8 __attribute__((ext_vector_type(8)));
typedef _Float16 f16x4 __attribute__((ext_vector_type(4)));
typedef float    f32x4 __attribute__((ext_vector_type(4)));

// ---------- fp32 -> fp16 conversion (single launch: X + 4 weights) ----------
__global__ __launch_bounds__(256)
void convert_kernel(const float* __restrict__ X, const float* __restrict__ w0,
                    const float* __restrict__ w1, const float* __restrict__ w2,
                    const float* __restrict__ w3,
                    _Float16* __restrict__ Xh, _Float16* __restrict__ Wh) {
  const int bi = blockIdx.x;
  const float* src; _Float16* dst; size_t off;
  if (bi < 4096) {                     // X: 8M f32
    src = X; dst = Xh; off = (size_t)bi * 2048;
  } else {                             // W0..W3: 1M f32 each
    const int wi = bi - 4096, z = wi >> 9;
    src = (z == 0) ? w0 : (z == 1) ? w1 : (z == 2) ? w2 : w3;
    dst = Wh + (size_t)z * HID * HID;
    off = (size_t)(wi & 511) * 2048;
  }
  const size_t i = off + (size_t)threadIdx.x * 8;
  f32x4 a = *(const f32x4*)(src + i);
  f32x4 b = *(const f32x4*)(src + i + 4);
  f16x8 o;
#pragma unroll
  for (int r = 0; r < 4; ++r) { o[r] = (_Float16)a[r]; o[r+4] = (_Float16)b[r]; }
  *(f16x8*)(dst + i) = o;
}

// async global->LDS, 16B per lane (m97-verified; LDS dest = uniform base + lane*16)
__device__ __forceinline__ void gload16(const void* g, void* lds) {
  __builtin_amdgcn_global_load_lds(
      (__attribute__((address_space(1))) void*)(void*)g,
      (__attribute__((address_space(3))) void*)lds, 16, 0, 0);
}

// ---------- C = A @ W^T main loop, BK=64 as two m97-pattern 8KB sub-tiles ----
// ROUND-8 note: R7's forced __launch_bounds__(256,4) spilled (WRITE +5MB,
// occupancy 28.5% not 50%, qkv 62->68). Reverted to (256,3): forcing regs
// down on this structure always nets negative (R3, R7). Occupancy gains
// must come organically from a smaller accumulator (see new o-proj).
__device__ __forceinline__ void gemm_mainloop(
    const _Float16* __restrict__ A, const _Float16* __restrict__ W,
    _Float16* sA, _Float16* sB, f32x4 (&acc)[4][4], int m0, int n0) {
  const int tid  = threadIdx.x;
  const int lane = tid & 63;
  const int wave = tid >> 6;
  const int wm = wave >> 1, wn = wave & 1;
  const int l15 = lane & 15, quad = lane >> 4;

  const int o0 = tid * 16;
  const int o1 = o0 + 4096;
  const _Float16* a0 = A + (size_t)(m0 + (o0 >> 6)) * HID + ((o0 & 63) >> 1);
  const _Float16* a1 = A + (size_t)(m0 + (o1 >> 6)) * HID + ((o1 & 63) >> 1);
  const _Float16* w0 = W + (size_t)(n0 + (o0 >> 6)) * HID + ((o0 & 63) >> 1);
  const _Float16* w1 = W + (size_t)(n0 + (o1 >> 6)) * HID + ((o1 & 63) >> 1);
  _Float16* la0 = sA + (o0 >> 1);
  _Float16* la1 = sA + (o1 >> 1);
  _Float16* lb0 = sB + (o0 >> 1);
  _Float16* lb1 = sB + (o1 >> 1);

  const int aoff = (wm*64 + l15)*32 + quad*8;
  const int boff = (wn*64 + l15)*32 + quad*8;

  for (int k0 = 0; k0 < HID; k0 += 64) {
    __syncthreads();                 // WAR: prior iter's LDS reads done
    gload16(a0 + k0,      la0);
    gload16(a1 + k0,      la1);
    gload16(a0 + k0 + 32, la0 + 4096);
    gload16(a1 + k0 + 32, la1 + 4096);
    gload16(w0 + k0,      lb0);
    gload16(w1 + k0,      lb1);
    gload16(w0 + k0 + 32, lb0 + 4096);
    gload16(w1 + k0 + 32, lb1 + 4096);
    __syncthreads();                 // staging complete
#pragma unroll
    for (int s = 0; s < 2; ++s) {
      const int sb = s * 4096;
      f16x8 af[4], wf[4];
#pragma unroll
      for (int t = 0; t < 4; ++t) {
        af[t] = *(const f16x8*)(sA + sb + aoff + t*512);
        wf[t] = *(const f16x8*)(sB + sb + boff + t*512);
      }
#pragma unroll
      for (int i = 0; i < 4; ++i)
#pragma unroll
        for (int j = 0; j < 4; ++j)
          acc[i][j] = __builtin_amdgcn_mfma_f32_16x16x32_f16(af[i], wf[j], acc[i][j], 0, 0, 0);
    }
  }
}

// QKV, 1536 blocks. XCD g owns X m-slab g (2MB L2-resident); W streams.
__global__ __launch_bounds__(256, 3)
void gemm_qkv_kernel(const _Float16* __restrict__ X,
                     const _Float16* __restrict__ Wh,
                     _Float16* __restrict__ Q,
                     _Float16* __restrict__ Kb,
                     _Float16* __restrict__ Vt) {
  __shared__ __align__(16) _Float16 sA[128*64];
  __shared__ __align__(16) _Float16 sB[128*64];
  const int i  = blockIdx.x;
  const int g  = i & 7;
  const int j  = i >> 3;
  const int mi = j & 7;
  const int c  = j >> 3;
  const int z  = c >> 3;
  const int n0 = (c & 7) * 128;
  const int m0 = (g*8 + mi) * 128;
  const _Float16* W = Wh + (size_t)z * HID * HID;
  f32x4 acc[4][4] = {};
  gemm_mainloop(X, W, sA, sB, acc, m0, n0);

  const int tid  = threadIdx.x;
  const int lane = tid & 63;
  const int wave = tid >> 6;
  const int wm = wave >> 1, wn = wave & 1;
  const int l15 = lane & 15, quad = lane >> 4;

  if (z < 2) {
    _Float16* C = (z == 0) ? Q : Kb;
    // z==0: fold softmax scale AND log2(e) into Q (exp2-domain softmax)
    const float scl = (z == 0) ? 0.18033688011f : 1.0f;
#pragma unroll
    for (int tm = 0; tm < 4; ++tm)
#pragma unroll
      for (int tn = 0; tn < 4; ++tn) {
        const int row = m0 + wm*64 + tm*16 + quad*4;
        const int col = n0 + wn*64 + tn*16 + l15;
#pragma unroll
        for (int r = 0; r < 4; ++r)
          C[(size_t)(row + r)*HID + col] = (_Float16)(acc[tm][tn][r] * scl);
      }
  } else {
#pragma unroll
    for (int tm = 0; tm < 4; ++tm)
#pragma unroll
      for (int tn = 0; tn < 4; ++tn) {
        const int row = m0 + wm*64 + tm*16 + quad*4;   // token
        const int col = n0 + wn*64 + tn*16 + l15;      // feature
        f16x4 v;
#pragma unroll
        for (int r = 0; r < 4; ++r) v[r] = (_Float16)acc[tm][tn][r];
        *(f16x4*)(Vt + (size_t)col*TOK + row) = v;
      }
  }
}

// ---------- O-proj, ROUND-8: 128x64 tiles, 1024 blocks ----------
// Organic occupancy: acc 4x2 (32 AGPR) + ~60 VGPR -> combined ~95 ->
// 5 waves/SIMD natural; LDS 24KB. Grid 1024 = 4 resident blocks/CU
// (vs hard 2 before) -> doubles cross-block hiding of the per-K-step
// vmcnt(0)+barrier drain. Cost: +50% ds_read per output (af4+wf2 for
// half the output) -- fine, phase is drain-limited not LDS-limited.
// B-staging: thread t stages row t>>2, k-chunk (t&3)*8 (+32 for half 1);
// LDS dest byte = (t>>2)*64+(t&3)*16 == 16*t  -> uniform base + lane*16 OK.
__global__ __launch_bounds__(256, 3)
void gemm_o_kernel(const _Float16* __restrict__ A,
                   const _Float16* __restrict__ Wo,
                   float* __restrict__ C) {
  __shared__ __align__(16) _Float16 sA[128*64];   // 16KB: two 8KB [128][32]
  __shared__ __align__(16) _Float16 sB[64*64];    // 8KB:  two 4KB [64][32]
  const int i  = blockIdx.x;
  const int g  = i & 7;                 // XCD
  const int j  = i >> 3;                // 0..127
  const int mi = j & 7;
  const int n0 = (j >> 3) * 64;         // 16 n-tiles of 64
  const int m0 = (g*8 + mi) * 128;      // 64 m-tiles, XCD-affine

  const int tid  = threadIdx.x;
  const int lane = tid & 63;
  const int wave = tid >> 6;
  const int wm = wave >> 1, wn = wave & 1;
  const int l15 = lane & 15, quad = lane >> 4;

  // A staging (same as mainloop)
  const int o0 = tid * 16;
  const int o1 = o0 + 4096;
  const _Float16* a0 = A + (size_t)(m0 + (o0 >> 6)) * HID + ((o0 & 63) >> 1);
  const _Float16* a1 = A + (size_t)(m0 + (o1 >> 6)) * HID + ((o1 & 63) >> 1);
  _Float16* la0 = sA + (o0 >> 1);
  _Float16* la1 = sA + (o1 >> 1);
  // B staging: row br = tid>>2, k-halfwords bk = (tid&3)*8
  const int br = tid >> 2;
  const int bk = (tid & 3) * 8;
  const _Float16* w0 = Wo + (size_t)(n0 + br) * HID + bk;
  _Float16* lb0 = sB + br*32 + bk;

  const int aoff = (wm*64 + l15)*32 + quad*8;
  const int boff = (wn*32 + l15)*32 + quad*8;

  f32x4 acc[4][2] = {};
  for (int k0 = 0; k0 < HID; k0 += 64) {
    __syncthreads();                 // WAR: prior iter's LDS reads done
    gload16(a0 + k0,      la0);
    gload16(a1 + k0,      la1);
    gload16(a0 + k0 + 32, la0 + 4096);
    gload16(a1 + k0 + 32, la1 + 4096);
    gload16(w0 + k0,      lb0);              // k-half 0 -> sB[0..4KB)
    gload16(w0 + k0 + 32, lb0 + 2048);       // k-half 1 -> sB[4KB..8KB)
    __syncthreads();                 // staging complete
#pragma unroll
    for (int s = 0; s < 2; ++s) {
      f16x8 af[4], wf[2];
#pragma unroll
      for (int t = 0; t < 4; ++t)
        af[t] = *(const f16x8*)(sA + s*4096 + aoff + t*512);
#pragma unroll
      for (int t = 0; t < 2; ++t)
        wf[t] = *(const f16x8*)(sB + s*2048 + boff + t*512);
#pragma unroll
      for (int ii = 0; ii < 4; ++ii)
#pragma unroll
        for (int jj = 0; jj < 2; ++jj)
          acc[ii][jj] = __builtin_amdgcn_mfma_f32_16x16x32_f16(af[ii], wf[jj], acc[ii][jj], 0, 0, 0);
    }
  }

  // epilogue: row = m0 + wm*64 + tm*16 + quad*4 + r; col = n0 + wn*32 + tn*16 + l15
#pragma unroll
  for (int tm = 0; tm < 4; ++tm)
#pragma unroll
    for (int tn = 0; tn < 2; ++tn) {
      const int row = m0 + wm*64 + tm*16 + quad*4;
      const int col = n0 + wn*32 + tn*16 + l15;
#pragma unroll
      for (int r = 0; r < 4; ++r)
        C[(size_t)(row + r)*HID + col] = acc[tm][tn][r];
    }
}

// ---------- Flash sliding-window attention, S^T orientation ----------
// (R6 structure kept verbatim: wave=16 queries, 128 q/block, grid 1024,
//  P buffer 8KB with chunk^(l15&3) swizzle, per-wave __all AM precheck,
//  LDS 40960B -> 4 blocks/CU = 32 waves/CU.)
__global__ __launch_bounds__(512, 4)
void attn_kernel(const _Float16* __restrict__ Q, const _Float16* __restrict__ Kb,
                 const _Float16* __restrict__ Vt, const int* __restrict__ AM,
                 _Float16* __restrict__ O) {
  __shared__ __align__(16) _Float16 sK[128*64];    // 16KB [key 0..127][d]
  __shared__ __align__(16) _Float16 sV[64*128];    // 16KB [dfeat][key 0..127]
  __shared__ __align__(16) _Float16 sP[8*16*32];   // 8KB  per-wave 16q x 32k

  const int bi = blockIdx.x;
  const int g  = bi & 7;                // XCD
  const int jj = bi >> 3;               // 0..127
  const int combo = g*4 + (jj >> 5);    // 0..31 -> (b,h), XCD-affine
  const int h = combo & 15, b = combo >> 4;
  const int qb = jj & 31;               // q-block (128 queries)

  const int tid  = threadIdx.x;
  const int lane = tid & 63, wave = tid >> 6;
  const int l15 = lane & 15, quad = lane >> 4;

  const int q0 = qb * 128;
  const int qw = q0 + wave * 16;        // wave's first (and only) q-tile

  const int swz = l15 & 7;
  const int cA8 = ((quad ^ swz) << 3);
  const int cB8 = (((quad + 4) ^ swz) << 3);

  // Q fragments: B[n=query=l15][k=d=quad*8+j]; Q pre-scaled by 0.125*log2(e).
  f16x8 qf0, qf1;
  {
    const size_t qbse = (size_t)(b*SEQ + qw + l15)*HID + h*HD + quad*8;
    qf0 = *(const f16x8*)(Q + qbse);
    qf1 = *(const f16x8*)(Q + qbse + 32);
  }

  // 128-key stages covering [stage_lo, q0+128)
  int stage_lo = (q0 - (WIN - 1));
  stage_lo = (stage_lo < 0) ? 0 : (stage_lo & ~127);
  const int nst = (q0 + 128 - stage_lo) >> 7;   // <= 5

  // per-wave attention_mask all-ones precheck (<=10 iters, no barriers)
  int okv = 1;
  for (int j = stage_lo + lane; j < q0 + 128; j += 64) okv &= (AM[b*SEQ + j] != 0);
  const bool allok = (__all(okv) != 0);

  // staging: thread stages 2x16B of K (rows prow, prow+64) and 2x16B of V.
  const int prow = tid >> 3;            // 0..63
  const int pc   = tid & 7;
  const int pco  = ((pc ^ (prow & 7)) << 3);   // swizzled GLOBAL chunk offset
  f16x8 pk0, pk1, pv0, pv1;
  {
    const _Float16* kp = Kb + (size_t)(b*SEQ + stage_lo + prow)*HID + h*HD + pco;
    pk0 = *(const f16x8*)kp;
    pk1 = *(const f16x8*)(kp + (size_t)64*HID);
    const _Float16* vp = Vt + (size_t)(h*HD + prow)*TOK + b*SEQ + stage_lo + pco;
    pv0 = *(const f16x8*)vp;
    pv1 = *(const f16x8*)(vp + 64);
  }

  float l_run = 0.0f;
  f32x4 o[4] = {};
  _Float16* myP = sP + wave * (16*32);

  for (int st = 0; st < nst; ++st) {
    const int j0st = stage_lo + st*128;
    __syncthreads();                  // WAR: prior iter's sK/sV reads done
    *(f16x8*)(sK + prow*64 + pc*8)        = pk0;   // UNSWIZZLED store position
    *(f16x8*)(sK + (64 + prow)*64 + pc*8) = pk1;
    *(f16x8*)(sV + prow*128 + pc*8)       = pv0;
    *(f16x8*)(sV + prow*128 + 64 + pc*8)  = pv1;
    __syncthreads();                  // staging visible
    if (st + 1 < nst) {
      const int jn = j0st + 128;
      const _Float16* kp = Kb + (size_t)(b*SEQ + jn + prow)*HID + h*HD + pco;
      pk0 = *(const f16x8*)kp;
      pk1 = *(const f16x8*)(kp + (size_t)64*HID);
      const _Float16* vp = Vt + (size_t)(h*HD + prow)*TOK + b*SEQ + jn + pco;
      pv0 = *(const f16x8*)vp;
      pv1 = *(const f16x8*)(vp + 64);
    }

#pragma unroll
    for (int s = 0; s < 2; ++s) {
      const int j0 = j0st + s*64;
      // wave-uniform: skip sub-tiles fully outside this wave's window
      if (j0 > qw + 15 || j0 + 63 < qw - (WIN - 1)) continue;
      // interior sub-tile: every (query,key) pair valid -> no mask needed
      const bool interior = (j0 + 63 <= qw) && (j0 >= qw - (WIN - 16));

      // S^T = K Q^T: sc[t] D[m=key=t*16+quad*4+r][n=query=l15]
      f32x4 sc[4];
#pragma unroll
      for (int t = 0; t < 4; ++t) {
        const f16x8 kf0 = *(const f16x8*)(sK + (s*64 + t*16 + l15)*64 + cA8);
        const f16x8 kf1 = *(const f16x8*)(sK + (s*64 + t*16 + l15)*64 + cB8);
        f32x4 a = {};
        a = __builtin_amdgcn_mfma_f32_16x16x32_f16(kf0, qf0, a, 0, 0, 0);
        a = __builtin_amdgcn_mfma_f32_16x16x32_f16(kf1, qf1, a, 0, 0, 0);
        sc[t] = a;
      }

      if (!allok) {
#pragma unroll
        for (int t = 0; t < 4; ++t)
#pragma unroll
          for (int r = 0; r < 4; ++r) {
            const float ad = (AM[b*SEQ + j0 + t*16 + quad*4 + r] == 0) ? -2e30f : 0.0f;
            sc[t][r] += ad;
          }
      }
      // window mask (boundary only) + static-bound softmax: p = exp2(s')
      if (!interior) {
        const int i = qw + l15;
#pragma unroll
        for (int t = 0; t < 4; ++t)
#pragma unroll
          for (int r = 0; r < 4; ++r) {
            const int j = j0 + t*16 + quad*4 + r;
            const bool valid = (unsigned)(i - j) < WIN;
            sc[t][r] = valid ? sc[t][r] : -1e30f;
          }
      }

      // per-32-key-half: exp2 -> P (1KB wave-private, chunk^(l15&3) swizzle)
      // -> PV MFMA. o accumulation order kh0,kh1 == old vf0,vf1 (bit-same).
      float sum = 0.0f;
#pragma unroll
      for (int kh = 0; kh < 2; ++kh) {
#pragma unroll
        for (int u = 0; u < 2; ++u) {
          const int t = 2*kh + u;
          f16x4 pvv;
#pragma unroll
          for (int r = 0; r < 4; ++r) {
            const float p = __builtin_amdgcn_exp2f(sc[t][r]);
            sum += p;
            pvv[r] = (_Float16)p;
          }
          // logical col (in 32-key half) = 16u + 4*quad + r; chunk-of-8 c =
          // 2u + (quad>>1), phys = c ^ (l15&3), in-chunk off = (quad&1)*4
          const int pch = (2*u + (quad >> 1)) ^ (l15 & 3);
          *(f16x4*)(myP + l15*32 + pch*8 + (quad & 1)*4) = pvv;
        }
        // B-frag: keys quad*8..+7 of this half -> phys chunk quad^(l15&3)
        const f16x8 pf = *(const f16x8*)(myP + l15*32 + ((quad ^ (l15 & 3)) << 3));
#pragma unroll
        for (int dt = 0; dt < 4; ++dt) {
          const f16x8 vf = *(const f16x8*)(sV + (dt*16 + l15)*128 + s*64 +
                                           (((kh*4 + quad) ^ swz) << 3));
          o[dt] = __builtin_amdgcn_mfma_f32_16x16x32_f16(vf, pf, o[dt], 0, 0, 0);
        }
      }
      sum += __shfl_xor(sum, 16, 64);
      sum += __shfl_xor(sum, 32, 64);
      l_run += sum;
    }
  }

  // epilogue: O^T[m=dfeat][n=query] -> O[query][feat]
  const float inv = 1.0f / fmaxf(l_run, 1e-30f);
  const size_t ob = (size_t)(b*SEQ + qw + l15)*HID + h*HD + quad*4;
#pragma unroll
  for (int dt = 0; dt < 4; ++dt) {
    f16x4 v;
#pragma unroll
    for (int r = 0; r < 4; ++r) v[r] = (_Float16)(o[dt][r] * inv);
    *(f16x4*)(O + ob + dt*16) = v;
  }
}

extern "C" void kernel_launch(void* const* d_in, const int* in_sizes, int n_in,
                              void* d_out, int out_size, void* d_ws, size_t ws_size,
                              hipStream_t stream) {
  const float* X  = (const float*)d_in[0];
  const int*   AM = (const int*)d_in[1];
  const float* Wq = (const float*)d_in[2];
  const float* Wk = (const float*)d_in[3];
  const float* Wv = (const float*)d_in[4];
  const float* Wo = (const float*)d_in[5];
  float* out = (float*)d_out;

  _Float16* Xh = (_Float16*)d_ws;
  _Float16* Wh = Xh + (size_t)TOK*HID;
  _Float16* Qb = Wh + (size_t)4*HID*HID;
  _Float16* Kb = Qb + (size_t)TOK*HID;
  _Float16* Vt = Kb + (size_t)TOK*HID;
  _Float16* AO = Vt + (size_t)TOK*HID;

  convert_kernel<<<dim3(4096 + 4*512), dim3(256), 0, stream>>>(X, Wq, Wk, Wv, Wo, Xh, Wh);
  gemm_qkv_kernel<<<dim3(1536), dim3(256), 0, stream>>>(Xh, Wh, Qb, Kb, Vt);
  attn_kernel<<<dim3(1024), dim3(512), 0, stream>>>(Qb, Kb, Vt, AM, AO);
  gemm_o_kernel<<<dim3(1024), dim3(256), 0, stream>>>(AO, Wh + (size_t)3*HID*HID, out);
}